// Round 3
// baseline (205.842 us; speedup 1.0000x reference)
//
#include <hip/hip_runtime.h>
#include <stdint.h>

typedef _Float16 f16x8 __attribute__((ext_vector_type(8)));
typedef _Float16 f16x2 __attribute__((ext_vector_type(2)));
typedef float f32x16 __attribute__((ext_vector_type(16)));
typedef unsigned int u32x4 __attribute__((ext_vector_type(4)));

#define T_OBS 50
#define PRED 12

// ws layout (f16 elements):
//   encA [T<4][kt<9][lane<64][j<8] = 18432   (kt 0..7 = W_hh K-tiles, kt 8 = [Wih|bias] x-tile)
//   decA same, +18432
//   fcA  [kt<8][lane<64][j<8] = 4096
#define DEC_OFF 18432
#define FC_OFF  36864
#define WS_ELEMS 40960

// Baked unit permutation: swap bits 2<->3 of the k-label. Makes the 32x32 C/D
// slot (row = (reg&3)+8*(reg>>2)+4*hi) land on the SAME lane-half (hi) as the
// B-frag slot that needs it next step: Bfrag[2T+(r>>3)][r&7] = tanh(acc[T][r]).
__device__ __forceinline__ int swap23(int k) {
  return (k & ~12) | ((k & 4) << 1) | ((k & 8) >> 1);
}

__global__ void prep_kernel(const float* __restrict__ Wih_e, const float* __restrict__ Whh_e,
                            const float* __restrict__ bih_e, const float* __restrict__ bhh_e,
                            const float* __restrict__ Wih_d, const float* __restrict__ Whh_d,
                            const float* __restrict__ bih_d, const float* __restrict__ bhh_d,
                            const float* __restrict__ fcW,
                            unsigned short* __restrict__ ws) {
  int idx = blockIdx.x * 256 + threadIdx.x;
  if (idx >= WS_ELEMS) return;
  float val = 0.0f;
  const int j = idx & 7;
  const int lane = (idx >> 3) & 63;
  const int hi = lane >> 5;
  const int mlo = lane & 31;
  if (idx < FC_OFF) {
    const bool enc = idx < DEC_OFF;
    const int e = enc ? idx : idx - DEC_OFF;
    const int rem = e >> 9;          // T*9 + kt
    const int kt = rem % 9;
    const int T = rem / 9;
    const int m = 32 * T + mlo;      // physical output unit (A-row = lane&31)
    const float* Wih = enc ? Wih_e : Wih_d;
    const float* Whh = enc ? Whh_e : Whh_d;
    const float* bih = enc ? bih_e : bih_d;
    const float* bhh = enc ? bhh_e : bhh_d;
    if (kt < 8) {
      const int kap = 16 * kt + 8 * hi + j;
      val = Whh[m * 128 + swap23(kap)];
    } else {
      const int c = 8 * hi + j;      // x-tile: x0,x1,x2,bias at c=0..3, rest 0
      if (c < 3) val = Wih[m * 3 + c];
      else if (c == 3) val = bih[m] + bhh[m];
    }
  } else {
    const int e = idx - FC_OFF;
    const int kt = e >> 9;           // 0..7
    const int kap = 16 * kt + 8 * hi + j;
    if (mlo < 3) val = fcW[mlo * 128 + swap23(kap)];   // rows 3..31 zero
  }
  _Float16 h = (_Float16)val;
  ws[idx] = __builtin_bit_cast(unsigned short, h);
}

__device__ __forceinline__ float tanh_fast(float v) {
  // tanh(v) = 1 - 2/(1 + e^{2v});  e^{2v} = exp2(v * 2*log2(e))
  float e = __builtin_amdgcn_exp2f(v * 2.8853900817779268f);
  return __builtin_fmaf(-2.0f, __builtin_amdgcn_rcpf(1.0f + e), 1.0f);
}

__device__ __forceinline__ unsigned int pk2(float a, float b) {
  return __builtin_bit_cast(unsigned int, __builtin_amdgcn_cvt_pkrtz(a, b));
}

__device__ __forceinline__ f16x8 ldfrag(const unsigned short* p) {
  return __builtin_bit_cast(f16x8, *(const u32x4*)p);
}

// Block = 2 waves (one pair), 32 seqs. Wave w owns m-tiles {2w,2w+1} (64 h-units)
// -> produces B-frags kt = 4w..4w+3. Pair exchange: 4x ds_write_b128 +
// 1 barrier + 4x ds_read_b128 per step, double-buffered.
__global__ __launch_bounds__(128, 2) void traj_kernel(
    const float* __restrict__ src, const unsigned short* __restrict__ ws,
    const float* __restrict__ fcb, float* __restrict__ out) {
  __shared__ unsigned short xch[2][2][4][64][8];   // [par][wave][frag][lane][8 f16]

  const int lane = (int)(threadIdx.x & 63u);
  const int w = (int)(threadIdx.x >> 6u);          // 0..1
  const int seq = blockIdx.x * 32 + (lane & 31);
  const int b = seq >> 6;                          // /64 agents
  const int a = seq & 63;

  // ---- A-frags for my two m-tiles: 18 frags (72 regs; AGPR-eligible) ----
  f16x8 A[2][9];
  #pragma unroll
  for (int t = 0; t < 2; ++t)
    #pragma unroll
    for (int kt = 0; kt < 9; ++kt)
      A[t][kt] = ldfrag(ws + (size_t)(((2 * w + t) * 9 + kt) * 64 + lane) * 8);

  const float* xq = src + (size_t)b * (T_OBS * 192) + a * 3;
  float x0 = xq[0], x1 = xq[1], x2 = xq[2];
  xq += 192;

  f16x8 Bf[8];
  #pragma unroll
  for (int kt = 0; kt < 8; ++kt) {
    u32x4 zz = (u32x4)0u;
    Bf[kt] = __builtin_bit_cast(f16x8, zz);        // h0 = 0
  }

  // xf: only k-slots 0..3 of hi=0 matter (A is zero elsewhere) -> no masking needed
  u32x4 xfu = (u32x4)0u;
  xfu[0] = pk2(x0, x1);
  xfu[1] = pk2(x2, 1.0f);

  const f32x16 z = (f32x16)0.0f;

  auto rnn_step = [&](int par) {
    f16x8 xf = __builtin_bit_cast(f16x8, xfu);
    // x/bias tile first (doesn't need Bf -> overlaps the exchange ds_reads)
    f32x16 a0 = __builtin_amdgcn_mfma_f32_32x32x16_f16(A[0][8], xf, z, 0, 0, 0);
    f32x16 a1 = __builtin_amdgcn_mfma_f32_32x32x16_f16(A[1][8], xf, z, 0, 0, 0);
    #pragma unroll
    for (int kt = 0; kt < 8; ++kt) {
      a0 = __builtin_amdgcn_mfma_f32_32x32x16_f16(A[0][kt], Bf[kt], a0, 0, 0, 0);
      a1 = __builtin_amdgcn_mfma_f32_32x32x16_f16(A[1][kt], Bf[kt], a1, 0, 0, 0);
    }
    // tanh + pack straight into B-frag layout (lane-local by the baked perm)
    u32x4 F0, F1, F2, F3;
    #pragma unroll
    for (int q = 0; q < 4; ++q) {
      F0[q] = pk2(tanh_fast(a0[2 * q]),     tanh_fast(a0[2 * q + 1]));
      F1[q] = pk2(tanh_fast(a0[8 + 2 * q]), tanh_fast(a0[8 + 2 * q + 1]));
      F2[q] = pk2(tanh_fast(a1[2 * q]),     tanh_fast(a1[2 * q + 1]));
      F3[q] = pk2(tanh_fast(a1[8 + 2 * q]), tanh_fast(a1[8 + 2 * q + 1]));
    }
    *(u32x4*)&xch[par][w][0][lane][0] = F0;
    *(u32x4*)&xch[par][w][1][lane][0] = F1;
    *(u32x4*)&xch[par][w][2][lane][0] = F2;
    *(u32x4*)&xch[par][w][3][lane][0] = F3;
    __syncthreads();
    if (w == 0) {
      Bf[0] = __builtin_bit_cast(f16x8, F0);
      Bf[1] = __builtin_bit_cast(f16x8, F1);
      Bf[2] = __builtin_bit_cast(f16x8, F2);
      Bf[3] = __builtin_bit_cast(f16x8, F3);
      Bf[4] = ldfrag(&xch[par][1][0][lane][0]);
      Bf[5] = ldfrag(&xch[par][1][1][lane][0]);
      Bf[6] = ldfrag(&xch[par][1][2][lane][0]);
      Bf[7] = ldfrag(&xch[par][1][3][lane][0]);
    } else {
      Bf[4] = __builtin_bit_cast(f16x8, F0);
      Bf[5] = __builtin_bit_cast(f16x8, F1);
      Bf[6] = __builtin_bit_cast(f16x8, F2);
      Bf[7] = __builtin_bit_cast(f16x8, F3);
      Bf[0] = ldfrag(&xch[par][0][0][lane][0]);
      Bf[1] = ldfrag(&xch[par][0][1][lane][0]);
      Bf[2] = ldfrag(&xch[par][0][2][lane][0]);
      Bf[3] = ldfrag(&xch[par][0][3][lane][0]);
    }
  };

  // ---- encoder: steps 0..48 with x-prefetch, step 49 peeled ----
  for (int s = 0; s < T_OBS - 1; ++s) {
    const float nx0 = xq[0], nx1 = xq[1], nx2 = xq[2];
    xq += 192;
    rnn_step(s & 1);
    xfu[0] = pk2(nx0, nx1);
    xfu[1] = pk2(nx2, 1.0f);
  }
  rnn_step(1);                      // s=49; xf keeps x[49] = decoder input 0

  // ---- decoder weights ----
  #pragma unroll
  for (int t = 0; t < 2; ++t)
    #pragma unroll
    for (int kt = 0; kt < 9; ++kt)
      A[t][kt] = ldfrag(ws + DEC_OFF + (size_t)(((2 * w + t) * 9 + kt) * 64 + lane) * 8);
  f16x8 Afc[8];
  #pragma unroll
  for (int kt = 0; kt < 8; ++kt)
    Afc[kt] = ldfrag(ws + FC_OFF + (size_t)(kt * 64 + lane) * 8);
  const float fb0 = fcb[0], fb1 = fcb[1], fb2 = fcb[2];

  float* op = out + (size_t)b * (PRED * 192) + a * 3;

  // ---- decoder: 12 autoregressive steps ----
  for (int p = 0; p < PRED; ++p) {
    rnn_step(p & 1);
    // fc head on updated h (both waves compute; only w0 stores)
    f32x16 pf = __builtin_amdgcn_mfma_f32_32x32x16_f16(Afc[0], Bf[0], z, 0, 0, 0);
    #pragma unroll
    for (int kt = 1; kt < 8; ++kt)
      pf = __builtin_amdgcn_mfma_f32_32x32x16_f16(Afc[kt], Bf[kt], pf, 0, 0, 0);
    const float p0 = pf[0] + fb0;   // fc rows 0..2 -> regs 0..2 on hi=0 lanes
    const float p1 = pf[1] + fb1;
    const float p2 = pf[2] + fb2;
    if (w == 0 && lane < 32) {
      op[p * 192 + 0] = p0;
      op[p * 192 + 1] = p1;
      op[p * 192 + 2] = p2;
    }
    // autoregressive feedback: garbage on hi=1 lanes is harmless (A zero there)
    xfu[0] = pk2(p0, p1);
    xfu[1] = pk2(p2, 1.0f);
  }
}

extern "C" void kernel_launch(void* const* d_in, const int* in_sizes, int n_in,
                              void* d_out, int out_size, void* d_ws, size_t ws_size,
                              hipStream_t stream) {
  const float* src   = (const float*)d_in[0];
  const float* Wih_e = (const float*)d_in[1];
  const float* Whh_e = (const float*)d_in[2];
  const float* bih_e = (const float*)d_in[3];
  const float* bhh_e = (const float*)d_in[4];
  const float* Wih_d = (const float*)d_in[5];
  const float* Whh_d = (const float*)d_in[6];
  const float* bih_d = (const float*)d_in[7];
  const float* bhh_d = (const float*)d_in[8];
  const float* fcW   = (const float*)d_in[9];
  const float* fcb   = (const float*)d_in[10];
  (void)in_sizes; (void)n_in; (void)out_size; (void)ws_size;

  unsigned short* ws = (unsigned short*)d_ws;

  prep_kernel<<<(WS_ELEMS + 255) / 256, 256, 0, stream>>>(
      Wih_e, Whh_e, bih_e, bhh_e, Wih_d, Whh_d, bih_d, bhh_d, fcW, ws);

  // 32768 seqs / 32 per block (pair of waves, M-split-2) = 1024 blocks
  traj_kernel<<<1024, 128, 0, stream>>>(src, ws, fcb, (float*)d_out);
}

// Round 4
// 99.016 us; speedup vs baseline: 2.0789x; 2.0789x over previous
//
#include <hip/hip_runtime.h>
#include <stdint.h>

typedef _Float16 f16x8 __attribute__((ext_vector_type(8)));
typedef float f32x4 __attribute__((ext_vector_type(4)));
typedef unsigned int u32x4 __attribute__((ext_vector_type(4)));

#define T_OBS 50
#define PRED 12

// ws layout (ushort == f16 bits):
//   enc frags: [t<8][kt<5][lane<64][j<8]   = 20480
//   dec frags: +20480
//   fc  frags: [kt<4][lane<64][j<8]        = 2048
#define DEC_OFF 20480
#define FC_OFF  40960
#define WS_ELEMS 43008

// kappa (physical A-column label) -> m (hidden-unit C/D-slot label)
// chosen so C/D slots feed B-frag slots with zero cross-lane movement.
__device__ __forceinline__ int unperm(int k) {
  return (k & 3) | (((k >> 3) & 3) << 2) | (((k >> 2) & 1) << 4) | (k & 0x60);
}

__global__ void prep_kernel(const float* __restrict__ Wih_e, const float* __restrict__ Whh_e,
                            const float* __restrict__ bih_e, const float* __restrict__ bhh_e,
                            const float* __restrict__ Wih_d, const float* __restrict__ Whh_d,
                            const float* __restrict__ bih_d, const float* __restrict__ bhh_d,
                            const float* __restrict__ fcW,
                            unsigned short* __restrict__ ws) {
  int idx = blockIdx.x * 256 + threadIdx.x;
  if (idx >= WS_ELEMS) return;
  float val = 0.0f;
  if (idx < FC_OFF) {
    const bool enc = idx < DEC_OFF;
    const int e = enc ? idx : idx - DEC_OFF;
    const int j = e & 7;
    const int lane = (e >> 3) & 63;
    const int rem = e >> 9;            // t*5 + kt
    const int kt = rem % 5;
    const int t = rem / 5;
    const int n = 16 * t + (lane & 15);
    const int kappa = 32 * kt + ((lane >> 4) << 3) + j;
    const float* Wih = enc ? Wih_e : Wih_d;
    const float* Whh = enc ? Whh_e : Whh_d;
    const float* bih = enc ? bih_e : bih_d;
    const float* bhh = enc ? bhh_e : bhh_d;
    if (kappa < 128)       val = Whh[n * 128 + unperm(kappa)];
    else if (kappa < 131)  val = Wih[n * 3 + (kappa - 128)];
    else if (kappa == 131) val = bih[n] + bhh[n];
    // kappa >= 132 -> 0 (padding)
  } else {
    const int e = idx - FC_OFF;
    const int j = e & 7;
    const int lane = (e >> 3) & 63;
    const int kt = e >> 9;             // 0..3 (h part only; fc bias added in VALU)
    const int o = lane & 15;
    const int kappa = 32 * kt + ((lane >> 4) << 3) + j;
    if (o < 3) val = fcW[o * 128 + unperm(kappa)];
  }
  _Float16 h = (_Float16)val;
  ws[idx] = __builtin_bit_cast(unsigned short, h);
}

__device__ __forceinline__ float tanh_fast(float v) {
  // tanh(v) = 1 - 2/(1 + e^{2v});  e^{2v} = exp2(v * 2*log2(e))
  float e = __builtin_amdgcn_exp2f(v * 2.8853900817779268f);
  return __builtin_fmaf(-2.0f, __builtin_amdgcn_rcpf(1.0f + e), 1.0f);
}

__device__ __forceinline__ unsigned int pk2(float a, float b) {
  return __builtin_bit_cast(unsigned int, __builtin_amdgcn_cvt_pkrtz(a, b));
}

__device__ __forceinline__ f16x8 ldfrag(const unsigned short* p) {
  return __builtin_bit_cast(f16x8, *(const u32x4*)p);
}

__device__ __forceinline__ f16x8 mkxf(float a, float b, float c) {
  u32x4 u;
  u[0] = pk2(a, b);
  u[1] = pk2(c, 1.0f);
  u[2] = 0u;
  u[3] = 0u;                // slots 4..7 unused (A zero there)
  return __builtin_bit_cast(f16x8, u);
}

// Block = 4 waves, 32 seqs (2 n-tiles). M-split-4: wave w owns m-tiles {2w,2w+1}
// -> produces B-frag kt=w for both n-tiles. K-tiles rotated per wave at LOAD
// time ((w+i)&3) so all register indices stay compile-time and the own-frag
// bypasses LDS. Per step: 2 ds_write_b128 + 1 barrier + 6 ds_read_b128.
// 1024 blocks x 4 waves = 4096 waves (~3/SIMD, 12 MFMA chains/SIMD).
__global__ __launch_bounds__(256, 3) void traj_kernel(
    const float* __restrict__ src, const unsigned short* __restrict__ ws,
    const float* __restrict__ fcb, float* __restrict__ out) {
  __shared__ unsigned short xch[2][4][2][64][8];   // [par][kt][ntile][lane][j] = 16KB

  const int lane = (int)(threadIdx.x & 63u);
  const int w = (int)(threadIdx.x >> 6u);          // 0..3
  const int l15 = lane & 15;
  const int sA = blockIdx.x * 32 + l15;            // n-tile 0 seq
  const int sB = sA + 16;                          // n-tile 1 seq
  const float* xpA = src + (size_t)(sA >> 6) * (T_OBS * 192) + (sA & 63) * 3;
  const float* xpB = src + (size_t)(sB >> 6) * (T_OBS * 192) + (sB & 63) * 3;

  // ---- A-frags for my two m-tiles, k-rotated: i<4 -> kt=(w+i)&3, i==4 -> x-tile ----
  f16x8 A0[5], A1[5];
  #pragma unroll
  for (int i = 0; i < 5; ++i) {
    const int kt = (i < 4) ? ((w + i) & 3) : 4;
    A0[i] = ldfrag(ws + (size_t)(((2 * w)     * 5 + kt) * 64 + lane) * 8);
    A1[i] = ldfrag(ws + (size_t)(((2 * w + 1) * 5 + kt) * 64 + lane) * 8);
  }

  f16x8 B0[4], B1[4];
  #pragma unroll
  for (int i = 0; i < 4; ++i) {
    u32x4 zz = (u32x4)0u;
    B0[i] = __builtin_bit_cast(f16x8, zz);         // h0 = 0
    B1[i] = __builtin_bit_cast(f16x8, zz);
  }

  f16x8 xf0 = mkxf(xpA[0], xpA[1], xpA[2]);
  f16x8 xf1 = mkxf(xpB[0], xpB[1], xpB[2]);

  // One RNN step: x-MFMAs first (independent of exchanged h -> fills LDS gap),
  // then 16 h-MFMAs (4 chains), tanh+pack, exchange.
  auto rnn_step = [&](int par, f16x8 xfa, f16x8 xfb) {
    const f32x4 z = (f32x4){0.f, 0.f, 0.f, 0.f};
    f32x4 aA = __builtin_amdgcn_mfma_f32_16x16x32_f16(A0[4], xfa, z, 0, 0, 0);
    f32x4 aB = __builtin_amdgcn_mfma_f32_16x16x32_f16(A1[4], xfa, z, 0, 0, 0);
    f32x4 aC = __builtin_amdgcn_mfma_f32_16x16x32_f16(A0[4], xfb, z, 0, 0, 0);
    f32x4 aD = __builtin_amdgcn_mfma_f32_16x16x32_f16(A1[4], xfb, z, 0, 0, 0);
    #pragma unroll
    for (int i = 0; i < 4; ++i) {
      aA = __builtin_amdgcn_mfma_f32_16x16x32_f16(A0[i], B0[i], aA, 0, 0, 0);
      aB = __builtin_amdgcn_mfma_f32_16x16x32_f16(A1[i], B0[i], aB, 0, 0, 0);
      aC = __builtin_amdgcn_mfma_f32_16x16x32_f16(A0[i], B1[i], aC, 0, 0, 0);
      aD = __builtin_amdgcn_mfma_f32_16x16x32_f16(A1[i], B1[i], aD, 0, 0, 0);
    }
    u32x4 F0, F1;
    F0[0] = pk2(tanh_fast(aA[0]), tanh_fast(aA[1]));
    F0[1] = pk2(tanh_fast(aA[2]), tanh_fast(aA[3]));
    F0[2] = pk2(tanh_fast(aB[0]), tanh_fast(aB[1]));
    F0[3] = pk2(tanh_fast(aB[2]), tanh_fast(aB[3]));
    F1[0] = pk2(tanh_fast(aC[0]), tanh_fast(aC[1]));
    F1[1] = pk2(tanh_fast(aC[2]), tanh_fast(aC[3]));
    F1[2] = pk2(tanh_fast(aD[0]), tanh_fast(aD[1]));
    F1[3] = pk2(tanh_fast(aD[2]), tanh_fast(aD[3]));
    *(u32x4*)&xch[par][w][0][lane][0] = F0;
    *(u32x4*)&xch[par][w][1][lane][0] = F1;
    __syncthreads();
    B0[0] = __builtin_bit_cast(f16x8, F0);         // own frag, kt=w == rotation i=0
    B1[0] = __builtin_bit_cast(f16x8, F1);
    #pragma unroll
    for (int i = 1; i < 4; ++i) {
      B0[i] = ldfrag(&xch[par][(w + i) & 3][0][lane][0]);
      B1[i] = ldfrag(&xch[par][(w + i) & 3][1][lane][0]);
    }
  };

  // ---- encoder: 50 steps, distance-1 x prefetch ----
  for (int s = 0; s < T_OBS; ++s) {
    const int t2 = (s < T_OBS - 1) ? s + 1 : s;    // clamp: ends with xf = x[49]
    const float na0 = xpA[t2 * 192], na1 = xpA[t2 * 192 + 1], na2 = xpA[t2 * 192 + 2];
    const float nb0 = xpB[t2 * 192], nb1 = xpB[t2 * 192 + 1], nb2 = xpB[t2 * 192 + 2];
    rnn_step(s & 1, xf0, xf1);
    xf0 = mkxf(na0, na1, na2);
    xf1 = mkxf(nb0, nb1, nb2);
  }

  // ---- decoder weights (same rotation) + fc frags ----
  #pragma unroll
  for (int i = 0; i < 5; ++i) {
    const int kt = (i < 4) ? ((w + i) & 3) : 4;
    A0[i] = ldfrag(ws + DEC_OFF + (size_t)(((2 * w)     * 5 + kt) * 64 + lane) * 8);
    A1[i] = ldfrag(ws + DEC_OFF + (size_t)(((2 * w + 1) * 5 + kt) * 64 + lane) * 8);
  }
  f16x8 Afc[4];
  #pragma unroll
  for (int i = 0; i < 4; ++i) {
    const int kt = (w + i) & 3;
    Afc[i] = ldfrag(ws + FC_OFF + (size_t)(kt * 64 + lane) * 8);
  }
  const float fb0 = fcb[0], fb1 = fcb[1], fb2 = fcb[2];

  float* opA = out + (size_t)(sA >> 6) * (PRED * 192) + (sA & 63) * 3;
  float* opB = out + (size_t)(sB >> 6) * (PRED * 192) + (sB & 63) * 3;

  // ---- decoder: 12 autoregressive steps ----
  for (int p = 0; p < PRED; ++p) {
    rnn_step(p & 1, xf0, xf1);
    const f32x4 z = (f32x4){0.f, 0.f, 0.f, 0.f};
    f32x4 pA = __builtin_amdgcn_mfma_f32_16x16x32_f16(Afc[0], B0[0], z, 0, 0, 0);
    f32x4 pB = __builtin_amdgcn_mfma_f32_16x16x32_f16(Afc[0], B1[0], z, 0, 0, 0);
    #pragma unroll
    for (int i = 1; i < 4; ++i) {
      pA = __builtin_amdgcn_mfma_f32_16x16x32_f16(Afc[i], B0[i], pA, 0, 0, 0);
      pB = __builtin_amdgcn_mfma_f32_16x16x32_f16(Afc[i], B1[i], pB, 0, 0, 0);
    }
    const float pa0 = pA[0] + fb0, pa1 = pA[1] + fb1, pa2 = pA[2] + fb2;
    const float pb0 = pB[0] + fb0, pb1 = pB[1] + fb1, pb2 = pB[2] + fb2;
    if (w == 0 && lane < 16) {                     // rows 0..2 live on lanes 0-15
      opA[p * 192 + 0] = pa0; opA[p * 192 + 1] = pa1; opA[p * 192 + 2] = pa2;
      opB[p * 192 + 0] = pb0; opB[p * 192 + 1] = pb1; opB[p * 192 + 2] = pb2;
    }
    // autoregressive feedback (valid on lanes<16; elsewhere harmless, A is 0)
    xf0 = mkxf(pa0, pa1, pa2);
    xf1 = mkxf(pb0, pb1, pb2);
  }
}

extern "C" void kernel_launch(void* const* d_in, const int* in_sizes, int n_in,
                              void* d_out, int out_size, void* d_ws, size_t ws_size,
                              hipStream_t stream) {
  const float* src   = (const float*)d_in[0];
  const float* Wih_e = (const float*)d_in[1];
  const float* Whh_e = (const float*)d_in[2];
  const float* bih_e = (const float*)d_in[3];
  const float* bhh_e = (const float*)d_in[4];
  const float* Wih_d = (const float*)d_in[5];
  const float* Whh_d = (const float*)d_in[6];
  const float* bih_d = (const float*)d_in[7];
  const float* bhh_d = (const float*)d_in[8];
  const float* fcW   = (const float*)d_in[9];
  const float* fcb   = (const float*)d_in[10];
  (void)in_sizes; (void)n_in; (void)out_size; (void)ws_size;

  unsigned short* ws = (unsigned short*)d_ws;

  prep_kernel<<<(WS_ELEMS + 255) / 256, 256, 0, stream>>>(
      Wih_e, Whh_e, bih_e, bhh_e, Wih_d, Whh_d, bih_d, bhh_d, fcW, ws);

  // 32768 seqs / 32 per block (M-split-4 x N=2 tiles) = 1024 blocks
  traj_kernel<<<1024, 256, 0, stream>>>(src, ws, fcb, (float*)d_out);
}

// Round 5
// 93.133 us; speedup vs baseline: 2.2102x; 1.0632x over previous
//
#include <hip/hip_runtime.h>
#include <stdint.h>

typedef _Float16 f16x8 __attribute__((ext_vector_type(8)));
typedef float f32x16 __attribute__((ext_vector_type(16)));
typedef unsigned int u32x4 __attribute__((ext_vector_type(4)));

#define T_OBS 50
#define PRED 12

// ws layout (f16 elements):
//   encA [T<4][kt<9][lane<64][j<8] = 18432   (kt 0..7 = W_hh K-tiles, kt 8 = [Wih|bias] x-tile)
//   decA same, +18432
//   fcA  [kt<8][lane<64][j<8] = 4096
#define DEC_OFF 18432
#define FC_OFF  36864
#define WS_ELEMS 40960

// Baked unit permutation: swap bits 2<->3 of the k-label. Makes the 32x32 C/D
// slot (row = (reg&3)+8*(reg>>2)+4*hi) land on the SAME lane-half (hi) as the
// B-frag slot that needs it next step: Bfrag[2T+(r>>3)][r&7] = tanh(acc[T][r]).
// (Verified end-to-end in R3: passed with absmax 0.0156.)
__device__ __forceinline__ int swap23(int k) {
  return (k & ~12) | ((k & 4) << 1) | ((k & 8) >> 1);
}

__global__ void prep_kernel(const float* __restrict__ Wih_e, const float* __restrict__ Whh_e,
                            const float* __restrict__ bih_e, const float* __restrict__ bhh_e,
                            const float* __restrict__ Wih_d, const float* __restrict__ Whh_d,
                            const float* __restrict__ bih_d, const float* __restrict__ bhh_d,
                            const float* __restrict__ fcW,
                            unsigned short* __restrict__ ws) {
  int idx = blockIdx.x * 256 + threadIdx.x;
  if (idx >= WS_ELEMS) return;
  float val = 0.0f;
  const int j = idx & 7;
  const int lane = (idx >> 3) & 63;
  const int hi = lane >> 5;
  const int mlo = lane & 31;
  if (idx < FC_OFF) {
    const bool enc = idx < DEC_OFF;
    const int e = enc ? idx : idx - DEC_OFF;
    const int rem = e >> 9;          // T*9 + kt
    const int kt = rem % 9;
    const int T = rem / 9;
    const int m = 32 * T + mlo;      // physical output unit (A-row = lane&31)
    const float* Wih = enc ? Wih_e : Wih_d;
    const float* Whh = enc ? Whh_e : Whh_d;
    const float* bih = enc ? bih_e : bih_d;
    const float* bhh = enc ? bhh_e : bhh_d;
    if (kt < 8) {
      const int kap = 16 * kt + 8 * hi + j;
      val = Whh[m * 128 + swap23(kap)];
    } else {
      const int c = 8 * hi + j;      // x-tile: x0,x1,x2,bias at c=0..3, rest 0
      if (c < 3) val = Wih[m * 3 + c];
      else if (c == 3) val = bih[m] + bhh[m];
    }
  } else {
    const int e = idx - FC_OFF;
    const int kt = e >> 9;           // 0..7
    const int kap = 16 * kt + 8 * hi + j;
    if (mlo < 3) val = fcW[mlo * 128 + swap23(kap)];   // rows 3..31 zero
  }
  _Float16 h = (_Float16)val;
  ws[idx] = __builtin_bit_cast(unsigned short, h);
}

__device__ __forceinline__ float tanh_fast(float v) {
  // tanh(v) = 1 - 2/(1 + e^{2v});  e^{2v} = exp2(v * 2*log2(e))
  float e = __builtin_amdgcn_exp2f(v * 2.8853900817779268f);
  return __builtin_fmaf(-2.0f, __builtin_amdgcn_rcpf(1.0f + e), 1.0f);
}

__device__ __forceinline__ unsigned int pk2(float a, float b) {
  return __builtin_bit_cast(unsigned int, __builtin_amdgcn_cvt_pkrtz(a, b));
}

__device__ __forceinline__ f16x8 ldfrag(const unsigned short* p) {
  return __builtin_bit_cast(f16x8, *(const u32x4*)p);
}

// Block = 4 waves = 2 independent PAIRS; each pair covers 32 seqs with
// M-split-2 (wave owns 2 m-tiles = 64 units -> produces 4 k-frags, trades 4
// with its partner). 512 blocks x 4 waves = 2048 waves = exactly 2/SIMD,
// SINGLE batch. Fragment positions use kt=(4*pw+i)&7 so own frags sit at
// i=0..3 and all register indices are compile-time.
__global__ __launch_bounds__(256, 2) void traj_kernel(
    const float* __restrict__ src, const unsigned short* __restrict__ ws,
    const float* __restrict__ fcb, float* __restrict__ out) {
  __shared__ unsigned short xch[2][2][2][4][64][8];  // [par][pair][pw][frag][lane][j] = 32KB

  const int lane = (int)(threadIdx.x & 63u);
  const int w = (int)(threadIdx.x >> 6u);            // 0..3
  const int pw = w & 1;                              // wave-in-pair
  const int pr = w >> 1;                             // pair id
  const int seq = blockIdx.x * 64 + pr * 32 + (lane & 31);
  const int b = seq >> 6;                            // /64 agents
  const int a = seq & 63;

  // ---- A-frags for my two m-tiles (mt = 2pw, 2pw+1): h-part at kt=(4pw+i)&7 ----
  f16x8 Ah[2][8], Ax[2];
  #pragma unroll
  for (int t = 0; t < 2; ++t) {
    const int mt = 2 * pw + t;
    #pragma unroll
    for (int i = 0; i < 8; ++i) {
      const int kt = (4 * pw + i) & 7;
      Ah[t][i] = ldfrag(ws + (size_t)((mt * 9 + kt) * 64 + lane) * 8);
    }
    Ax[t] = ldfrag(ws + (size_t)((mt * 9 + 8) * 64 + lane) * 8);
  }

  const float* xq = src + (size_t)b * (T_OBS * 192) + a * 3;
  float x0 = xq[0], x1 = xq[1], x2 = xq[2];
  xq += 192;

  f16x8 Bl[8];
  #pragma unroll
  for (int i = 0; i < 8; ++i) {
    u32x4 zz = (u32x4)0u;
    Bl[i] = __builtin_bit_cast(f16x8, zz);           // h0 = 0
  }

  // xf: only k-slots 0..3 on hi=0 lanes matter (A zero elsewhere)
  u32x4 xfu = (u32x4)0u;
  xfu[0] = pk2(x0, x1);
  xfu[1] = pk2(x2, 1.0f);

  auto rnn_step = [&](int par) {
    const f32x16 z = (f32x16)0.0f;
    f16x8 xf = __builtin_bit_cast(f16x8, xfu);
    // x/bias tile first: independent of exchanged h -> overlaps barrier/ds_read
    f32x16 a0 = __builtin_amdgcn_mfma_f32_32x32x16_f16(Ax[0], xf, z, 0, 0, 0);
    f32x16 a1 = __builtin_amdgcn_mfma_f32_32x32x16_f16(Ax[1], xf, z, 0, 0, 0);
    #pragma unroll
    for (int i = 0; i < 8; ++i) {
      a0 = __builtin_amdgcn_mfma_f32_32x32x16_f16(Ah[0][i], Bl[i], a0, 0, 0, 0);
      a1 = __builtin_amdgcn_mfma_f32_32x32x16_f16(Ah[1][i], Bl[i], a1, 0, 0, 0);
    }
    // tanh + pack straight into B-frag layout (lane-local by the baked perm)
    u32x4 F0, F1, F2, F3;
    #pragma unroll
    for (int q = 0; q < 4; ++q) {
      F0[q] = pk2(tanh_fast(a0[2 * q]),     tanh_fast(a0[2 * q + 1]));
      F1[q] = pk2(tanh_fast(a0[8 + 2 * q]), tanh_fast(a0[8 + 2 * q + 1]));
      F2[q] = pk2(tanh_fast(a1[2 * q]),     tanh_fast(a1[2 * q + 1]));
      F3[q] = pk2(tanh_fast(a1[8 + 2 * q]), tanh_fast(a1[8 + 2 * q + 1]));
    }
    *(u32x4*)&xch[par][pr][pw][0][lane][0] = F0;
    *(u32x4*)&xch[par][pr][pw][1][lane][0] = F1;
    *(u32x4*)&xch[par][pr][pw][2][lane][0] = F2;
    *(u32x4*)&xch[par][pr][pw][3][lane][0] = F3;
    __syncthreads();
    Bl[0] = __builtin_bit_cast(f16x8, F0);           // own frags: i=0..3
    Bl[1] = __builtin_bit_cast(f16x8, F1);
    Bl[2] = __builtin_bit_cast(f16x8, F2);
    Bl[3] = __builtin_bit_cast(f16x8, F3);
    Bl[4] = ldfrag(&xch[par][pr][pw ^ 1][0][lane][0]);  // partner frags: i=4..7
    Bl[5] = ldfrag(&xch[par][pr][pw ^ 1][1][lane][0]);
    Bl[6] = ldfrag(&xch[par][pr][pw ^ 1][2][lane][0]);
    Bl[7] = ldfrag(&xch[par][pr][pw ^ 1][3][lane][0]);
  };

  // ---- encoder: steps 0..48 with distance-1 x prefetch, step 49 peeled ----
  for (int s = 0; s < T_OBS - 1; ++s) {
    const float nx0 = xq[0], nx1 = xq[1], nx2 = xq[2];
    xq += 192;
    rnn_step(s & 1);
    xfu[0] = pk2(nx0, nx1);
    xfu[1] = pk2(nx2, 1.0f);
  }
  rnn_step(1);                      // s=49; xfu keeps x[49] = decoder input 0

  // ---- decoder weights (same kt rotation) + fc frags ----
  #pragma unroll
  for (int t = 0; t < 2; ++t) {
    const int mt = 2 * pw + t;
    #pragma unroll
    for (int i = 0; i < 8; ++i) {
      const int kt = (4 * pw + i) & 7;
      Ah[t][i] = ldfrag(ws + DEC_OFF + (size_t)((mt * 9 + kt) * 64 + lane) * 8);
    }
    Ax[t] = ldfrag(ws + DEC_OFF + (size_t)((mt * 9 + 8) * 64 + lane) * 8);
  }
  f16x8 Afc[8];
  #pragma unroll
  for (int i = 0; i < 8; ++i) {
    const int kt = (4 * pw + i) & 7;
    Afc[i] = ldfrag(ws + FC_OFF + (size_t)(kt * 64 + lane) * 8);
  }
  const float fb0 = fcb[0], fb1 = fcb[1], fb2 = fcb[2];

  float* op = out + (size_t)b * (PRED * 192) + a * 3;

  // ---- decoder: 12 autoregressive steps ----
  for (int p = 0; p < PRED; ++p) {
    rnn_step(p & 1);
    // fc head on updated h (both waves of the pair compute; pw==0 stores)
    const f32x16 z = (f32x16)0.0f;
    f32x16 pf = __builtin_amdgcn_mfma_f32_32x32x16_f16(Afc[0], Bl[0], z, 0, 0, 0);
    #pragma unroll
    for (int i = 1; i < 8; ++i)
      pf = __builtin_amdgcn_mfma_f32_32x32x16_f16(Afc[i], Bl[i], pf, 0, 0, 0);
    const float p0 = pf[0] + fb0;   // fc rows 0..2 -> regs 0..2 on hi=0 lanes
    const float p1 = pf[1] + fb1;
    const float p2 = pf[2] + fb2;
    if (pw == 0 && lane < 32) {
      op[p * 192 + 0] = p0;
      op[p * 192 + 1] = p1;
      op[p * 192 + 2] = p2;
    }
    // autoregressive feedback (valid on hi=0 lanes; hi=1 junk harmless, A zero)
    xfu[0] = pk2(p0, p1);
    xfu[1] = pk2(p2, 1.0f);
  }
}

extern "C" void kernel_launch(void* const* d_in, const int* in_sizes, int n_in,
                              void* d_out, int out_size, void* d_ws, size_t ws_size,
                              hipStream_t stream) {
  const float* src   = (const float*)d_in[0];
  const float* Wih_e = (const float*)d_in[1];
  const float* Whh_e = (const float*)d_in[2];
  const float* bih_e = (const float*)d_in[3];
  const float* bhh_e = (const float*)d_in[4];
  const float* Wih_d = (const float*)d_in[5];
  const float* Whh_d = (const float*)d_in[6];
  const float* bih_d = (const float*)d_in[7];
  const float* bhh_d = (const float*)d_in[8];
  const float* fcW   = (const float*)d_in[9];
  const float* fcb   = (const float*)d_in[10];
  (void)in_sizes; (void)n_in; (void)out_size; (void)ws_size;

  unsigned short* ws = (unsigned short*)d_ws;

  prep_kernel<<<(WS_ELEMS + 255) / 256, 256, 0, stream>>>(
      Wih_e, Whh_e, bih_e, bhh_e, Wih_d, Whh_d, bih_d, bhh_d, fcW, ws);

  // 32768 seqs / 64 per block (2 pairs x 32 seqs, M-split-2) = 512 blocks
  traj_kernel<<<512, 256, 0, stream>>>(src, ws, fcb, (float*)d_out);
}